// Round 5
// baseline (417.621 us; speedup 1.0000x reference)
//
#include <hip/hip_runtime.h>

#define DN 64
#define DE 32
#define DO 64
#define NB 256   // scan phase-1 blocks (requires n_nodes <= NB*256)
#define WPB 4    // waves per block in agg

// ---------------------------------------------------------------------------
// K1: per-node projections through the edge-MLP weight:
//   Ps[n] = node[n] @ W_e[0:64], Pd[n] = node[n] @ W_e[96:160]
// ---------------------------------------------------------------------------
__global__ void __launch_bounds__(256) node_pre_kernel(
    const float* __restrict__ node, const float* __restrict__ W_e,
    float* __restrict__ Ps, float* __restrict__ Pd, int n_nodes)
{
    const int lane = threadIdx.x & 63;
    const int wid  = __builtin_amdgcn_readfirstlane((int)(threadIdx.x >> 6));
    const int wpb  = blockDim.x >> 6;
    const int gw   = blockIdx.x * wpb + wid;
    const int nw   = gridDim.x * wpb;

    float Ws[64], Wd[64];
#pragma unroll
    for (int k = 0; k < 64; ++k) {
        Ws[k] = W_e[k * DO + lane];
        Wd[k] = W_e[(96 + k) * DO + lane];
    }

    for (int n = gw; n < n_nodes; n += nw) {
        const float* __restrict__ x = node + (size_t)n * DN;
        float as = 0.f, ad = 0.f;
#pragma unroll
        for (int k = 0; k < 64; ++k) {
            const float xk = x[k];
            as = fmaf(xk, Ws[k], as);
            ad = fmaf(xk, Wd[k], ad);
        }
        Ps[(size_t)n * DO + lane] = as;
        Pd[(size_t)n * DO + lane] = ad;
    }
}

// ---------------------------------------------------------------------------
// K2: degree histogram
// ---------------------------------------------------------------------------
__global__ void __launch_bounds__(256) hist_kernel(
    const int* __restrict__ dst, int* __restrict__ cnt, int n_edges)
{
    int e = blockIdx.x * blockDim.x + threadIdx.x;
    if (e < n_edges) atomicAdd(&cnt[dst[e]], 1);
}

// ---------------------------------------------------------------------------
// K3a: per-block local exclusive scan of cnt chunks + block sums.
// ---------------------------------------------------------------------------
__global__ void __launch_bounds__(256) scan_partial(
    const int* __restrict__ cnt, int* __restrict__ local,
    int* __restrict__ bsum, int n_nodes)
{
    const int C = (n_nodes + NB - 1) / NB;
    const int t = threadIdx.x, lane = t & 63, w = t >> 6;
    const int i = blockIdx.x * C + t;

    int v = (t < C && i < n_nodes) ? cnt[i] : 0;
    int incl = v;
#pragma unroll
    for (int off = 1; off < 64; off <<= 1) {
        int u = __shfl_up(incl, off, 64);
        if (lane >= off) incl += u;
    }
    __shared__ int ws[4], wo[4];
    if (lane == 63) ws[w] = incl;
    __syncthreads();
    if (t == 0) {
        int r = 0;
#pragma unroll
        for (int q = 0; q < 4; ++q) { wo[q] = r; r += ws[q]; }
        bsum[blockIdx.x] = r;
    }
    __syncthreads();
    if (t < C && i < n_nodes) local[i] = incl - v + wo[w];
}

// ---------------------------------------------------------------------------
// K3b: exclusive scan of the NB block sums (one block)
// ---------------------------------------------------------------------------
__global__ void __launch_bounds__(NB) scan_bsum(
    int* __restrict__ bsum, int* __restrict__ row_start, int n_nodes)
{
    const int t = threadIdx.x, lane = t & 63, w = t >> 6;
    int v = bsum[t];
    int incl = v;
#pragma unroll
    for (int off = 1; off < 64; off <<= 1) {
        int u = __shfl_up(incl, off, 64);
        if (lane >= off) incl += u;
    }
    __shared__ int ws[4], wo[4];
    if (lane == 63) ws[w] = incl;
    __syncthreads();
    if (t == 0) {
        int r = 0;
#pragma unroll
        for (int q = 0; q < 4; ++q) { wo[q] = r; r += ws[q]; }
    }
    __syncthreads();
    int excl = incl - v + wo[w];
    bsum[t] = excl;
    if (t == NB - 1) row_start[n_nodes] = excl + v;
}

// ---------------------------------------------------------------------------
// K3c: combine local prefixes + block offsets -> row_start, cursor
// ---------------------------------------------------------------------------
__global__ void __launch_bounds__(256) scan_add(
    const int* __restrict__ local, const int* __restrict__ bsum,
    int* __restrict__ row_start, int* __restrict__ cursor, int n_nodes)
{
    const int C = (n_nodes + NB - 1) / NB;
    const int i = blockIdx.x * C + threadIdx.x;
    if (threadIdx.x < C && i < n_nodes) {
        int r = local[i] + bsum[blockIdx.x];
        row_start[i] = r;
        cursor[i]    = r;
    }
}

// ---------------------------------------------------------------------------
// K4: scatter edge ids into CSR order
// ---------------------------------------------------------------------------
__global__ void __launch_bounds__(256) scatter_kernel(
    const int* __restrict__ dst, int* __restrict__ cursor,
    int* __restrict__ eidx, int n_edges)
{
    int e = blockIdx.x * blockDim.x + threadIdx.x;
    if (e < n_edges) {
        int p = atomicAdd(&cursor[dst[e]], 1);
        eidx[p] = e;
    }
}

// ---------------------------------------------------------------------------
// K5: fused edge-message + per-node aggregation. Wave per node.
// Per 64-edge batch: lane-parallel load of eidx/src (no dependent chains),
// reg-staged copy of the 64 edge rows into LDS (coalesced, 8 lanes x float4
// per row), then compute loop reads er via UNIFORM-address ds_read_b128
// (pure broadcast, conflict-free) and src via uniform LDS read. The only
// latency-bearing op per edge is the Ps[src] gather (coalesced 256B row),
// overlapped via unroll + 16 waves/CU.
// ---------------------------------------------------------------------------
__global__ void __launch_bounds__(256) agg_kernel(
    const float* __restrict__ edge, const int* __restrict__ src,
    const float* __restrict__ W_e, const float* __restrict__ b_e,
    const float* __restrict__ Ps, const float* __restrict__ Pd,
    const int* __restrict__ row_start, const int* __restrict__ eidx,
    float* __restrict__ msum, int n_nodes)
{
    __shared__ float lds_er[WPB][64][32];   // 32 KB
    __shared__ int   lds_e[WPB][64];        // 1 KB
    __shared__ int   lds_s[WPB][64];        // 1 KB

    const int lane = threadIdx.x & 63;
    const int wid  = threadIdx.x >> 6;
    const int n    = blockIdx.x * WPB + wid;
    if (n >= n_nodes) return;

    float Wm[32];
#pragma unroll
    for (int k = 0; k < 32; ++k)
        Wm[k] = W_e[(64 + k) * DO + lane];

    const float base_m = b_e[lane] + Pd[(unsigned)n * DO + lane];
    const int beg = row_start[n], end = row_start[n + 1];

    float acc = 0.f;
    for (int b0 = beg; b0 < end; b0 += 64) {
        const int cnt = min(end - b0, 64);
        const int idx = min(b0 + lane, end - 1);
        const int e = eidx[idx];                 // lane-parallel, coalesced
        const int s = src[e];                    // lane-parallel gather
        lds_e[wid][lane] = e;
        lds_s[wid][lane] = s;
        // wave-synchronous: same wave writes then reads; compiler inserts
        // the lgkmcnt wait (no barrier needed, slices are per-wave).

        // stage 64 edge rows: 8 lanes per row, 8 rows per pass
        const int rr = lane >> 3;
        const int cc = (lane & 7) << 2;          // float col: 0,4,..,28
#pragma unroll
        for (int p = 0; p < 8; ++p) {
            const int row = p * 8 + rr;
            const int eid = lds_e[wid][row];     // 8 distinct addrs: broadcast groups
            const float4 v = *(const float4*)(edge + (size_t)eid * DE + cc);
            *(float4*)(&lds_er[wid][row][cc]) = v;
        }

#pragma unroll 4
        for (int j = 0; j < cnt; ++j) {
            const int sj = lds_s[wid][j];                    // uniform addr
            const float ps = Ps[(unsigned)sj * DO + lane];   // coalesced gather
            const float* __restrict__ lrow = &lds_er[wid][j][0];
            float m0 = base_m + ps, m1 = 0.f, m2 = 0.f, m3 = 0.f;
#pragma unroll
            for (int k = 0; k < 32; k += 4) {
                m0 = fmaf(lrow[k],     Wm[k],     m0);
                m1 = fmaf(lrow[k + 1], Wm[k + 1], m1);
                m2 = fmaf(lrow[k + 2], Wm[k + 2], m2);
                m3 = fmaf(lrow[k + 3], Wm[k + 3], m3);
            }
            acc += fmaxf((m0 + m1) + (m2 + m3), 0.f);
        }
    }
    msum[(unsigned)n * DO + lane] = acc;
}

// ---------------------------------------------------------------------------
// K6: node update: out = relu((msum/deg)@W_v[0:64] + node@W_v[64:128] + b_v)
// ---------------------------------------------------------------------------
__global__ void __launch_bounds__(256) node_out_kernel(
    const float* __restrict__ node, const float* __restrict__ msum,
    const int* __restrict__ row_start,
    const float* __restrict__ W_v, const float* __restrict__ b_v,
    float* __restrict__ out, int n_nodes)
{
    const int lane = threadIdx.x & 63;
    const int wid  = __builtin_amdgcn_readfirstlane((int)(threadIdx.x >> 6));
    const int wpb  = blockDim.x >> 6;
    const int gw   = blockIdx.x * wpb + wid;
    const int nw   = gridDim.x * wpb;

    float Wt[64], Wb[64];
#pragma unroll
    for (int k = 0; k < 64; ++k) {
        Wt[k] = W_v[k * DO + lane];
        Wb[k] = W_v[(64 + k) * DO + lane];
    }
    const float bj = b_v[lane];

    for (int n = gw; n < n_nodes; n += nw) {
        const float* __restrict__ ms = msum + (size_t)n * DO;
        const float* __restrict__ x  = node + (size_t)n * DN;
        const float dg = (float)(row_start[n + 1] - row_start[n]);
        float an = 0.f, ax = 0.f;
#pragma unroll
        for (int k = 0; k < 64; ++k) {
            an = fmaf(ms[k], Wt[k], an);
            ax = fmaf(x[k],  Wb[k], ax);
        }
        float acc = bj + ax + (dg > 0.f ? an / dg : 0.f);
        out[(size_t)n * DO + lane] = fmaxf(acc, 0.f);
    }
}

extern "C" void kernel_launch(void* const* d_in, const int* in_sizes, int n_in,
                              void* d_out, int out_size, void* d_ws, size_t ws_size,
                              hipStream_t stream)
{
    const float* node = (const float*)d_in[0];
    const float* edge = (const float*)d_in[1];
    const int*   src  = (const int*)d_in[2];
    const int*   dst  = (const int*)d_in[3];
    const float* W_e  = (const float*)d_in[4];
    const float* b_e  = (const float*)d_in[5];
    const float* W_v  = (const float*)d_in[6];
    const float* b_v  = (const float*)d_in[7];
    float* out = (float*)d_out;

    const int n_nodes = in_sizes[0] / DN;
    const int n_edges = in_sizes[2];

    // Workspace: Ps | Pd | msum (floats) | row_start | cnt | cursor | eidx | local | bsum
    float* Ps   = (float*)d_ws;
    float* Pd   = Ps   + (size_t)n_nodes * DO;
    float* msum = Pd   + (size_t)n_nodes * DO;
    int* row_start = (int*)(msum + (size_t)n_nodes * DO);
    int* cnt       = row_start + (n_nodes + 1);
    int* cursor    = cnt + n_nodes;
    int* eidx      = cursor + n_nodes;
    int* local     = eidx + n_edges;
    int* bsum      = local + n_nodes;

    hipMemsetAsync(cnt, 0, (size_t)n_nodes * sizeof(int), stream);

    node_pre_kernel<<<512, 256, 0, stream>>>(node, W_e, Ps, Pd, n_nodes);
    hist_kernel<<<(n_edges + 255) / 256, 256, 0, stream>>>(dst, cnt, n_edges);
    scan_partial<<<NB, 256, 0, stream>>>(cnt, local, bsum, n_nodes);
    scan_bsum<<<1, NB, 0, stream>>>(bsum, row_start, n_nodes);
    scan_add<<<NB, 256, 0, stream>>>(local, bsum, row_start, cursor, n_nodes);
    scatter_kernel<<<(n_edges + 255) / 256, 256, 0, stream>>>(dst, cursor, eidx, n_edges);
    agg_kernel<<<(n_nodes + WPB - 1) / WPB, 256, 0, stream>>>(edge, src, W_e, b_e, Ps, Pd,
                                                              row_start, eidx, msum, n_nodes);
    node_out_kernel<<<512, 256, 0, stream>>>(node, msum, row_start, W_v, b_v,
                                             out, n_nodes);
}

// Round 6
// 385.805 us; speedup vs baseline: 1.0825x; 1.0825x over previous
//
#include <hip/hip_runtime.h>

#define DN 64
#define DE 32
#define DO 64
#define NB 256   // scan phase-1 blocks (requires n_nodes <= NB*256)

// ---------------------------------------------------------------------------
// K1: per-node projections through the edge-MLP weight:
//   Ps[n] = node[n] @ W_e[0:64], Pd[n] = node[n] @ W_e[96:160]
// ---------------------------------------------------------------------------
__global__ void __launch_bounds__(256) node_pre_kernel(
    const float* __restrict__ node, const float* __restrict__ W_e,
    float* __restrict__ Ps, float* __restrict__ Pd, int n_nodes)
{
    const int lane = threadIdx.x & 63;
    const int wid  = __builtin_amdgcn_readfirstlane((int)(threadIdx.x >> 6));
    const int wpb  = blockDim.x >> 6;
    const int gw   = blockIdx.x * wpb + wid;
    const int nw   = gridDim.x * wpb;

    float Ws[64], Wd[64];
#pragma unroll
    for (int k = 0; k < 64; ++k) {
        Ws[k] = W_e[k * DO + lane];
        Wd[k] = W_e[(96 + k) * DO + lane];
    }

    for (int n = gw; n < n_nodes; n += nw) {
        const float* __restrict__ x = node + (size_t)n * DN;
        float as = 0.f, ad = 0.f;
#pragma unroll
        for (int k = 0; k < 64; ++k) {
            const float xk = x[k];
            as = fmaf(xk, Ws[k], as);
            ad = fmaf(xk, Wd[k], ad);
        }
        Ps[(size_t)n * DO + lane] = as;
        Pd[(size_t)n * DO + lane] = ad;
    }
}

// ---------------------------------------------------------------------------
// K2: degree histogram
// ---------------------------------------------------------------------------
__global__ void __launch_bounds__(256) hist_kernel(
    const int* __restrict__ dst, int* __restrict__ cnt, int n_edges)
{
    int e = blockIdx.x * blockDim.x + threadIdx.x;
    if (e < n_edges) atomicAdd(&cnt[dst[e]], 1);
}

// ---------------------------------------------------------------------------
// K3a: per-block local exclusive scan of cnt chunks + block sums.
// ---------------------------------------------------------------------------
__global__ void __launch_bounds__(256) scan_partial(
    const int* __restrict__ cnt, int* __restrict__ local,
    int* __restrict__ bsum, int n_nodes)
{
    const int C = (n_nodes + NB - 1) / NB;
    const int t = threadIdx.x, lane = t & 63, w = t >> 6;
    const int i = blockIdx.x * C + t;

    int v = (t < C && i < n_nodes) ? cnt[i] : 0;
    int incl = v;
#pragma unroll
    for (int off = 1; off < 64; off <<= 1) {
        int u = __shfl_up(incl, off, 64);
        if (lane >= off) incl += u;
    }
    __shared__ int ws[4], wo[4];
    if (lane == 63) ws[w] = incl;
    __syncthreads();
    if (t == 0) {
        int r = 0;
#pragma unroll
        for (int q = 0; q < 4; ++q) { wo[q] = r; r += ws[q]; }
        bsum[blockIdx.x] = r;
    }
    __syncthreads();
    if (t < C && i < n_nodes) local[i] = incl - v + wo[w];
}

// ---------------------------------------------------------------------------
// K3b: exclusive scan of the NB block sums (one block)
// ---------------------------------------------------------------------------
__global__ void __launch_bounds__(NB) scan_bsum(
    int* __restrict__ bsum, int* __restrict__ row_start, int n_nodes)
{
    const int t = threadIdx.x, lane = t & 63, w = t >> 6;
    int v = bsum[t];
    int incl = v;
#pragma unroll
    for (int off = 1; off < 64; off <<= 1) {
        int u = __shfl_up(incl, off, 64);
        if (lane >= off) incl += u;
    }
    __shared__ int ws[4], wo[4];
    if (lane == 63) ws[w] = incl;
    __syncthreads();
    if (t == 0) {
        int r = 0;
#pragma unroll
        for (int q = 0; q < 4; ++q) { wo[q] = r; r += ws[q]; }
    }
    __syncthreads();
    int excl = incl - v + wo[w];
    bsum[t] = excl;
    if (t == NB - 1) row_start[n_nodes] = excl + v;
}

// ---------------------------------------------------------------------------
// K3c: combine local prefixes + block offsets -> row_start, cursor
// ---------------------------------------------------------------------------
__global__ void __launch_bounds__(256) scan_add(
    const int* __restrict__ local, const int* __restrict__ bsum,
    int* __restrict__ row_start, int* __restrict__ cursor, int n_nodes)
{
    const int C = (n_nodes + NB - 1) / NB;
    const int i = blockIdx.x * C + threadIdx.x;
    if (threadIdx.x < C && i < n_nodes) {
        int r = local[i] + bsum[blockIdx.x];
        row_start[i] = r;
        cursor[i]    = r;
    }
}

// ---------------------------------------------------------------------------
// K4: scatter (edge_id, src_id) int2 pairs into CSR order. src[e] read is
// coalesced here (e linear), killing the dependent src gather in agg.
// ---------------------------------------------------------------------------
__global__ void __launch_bounds__(256) scatter_kernel(
    const int* __restrict__ dst, const int* __restrict__ src,
    int* __restrict__ cursor, int2* __restrict__ csr, int n_edges)
{
    int e = blockIdx.x * blockDim.x + threadIdx.x;
    if (e < n_edges) {
        int p = atomicAdd(&cursor[dst[e]], 1);
        csr[p] = make_int2(e, src[e]);
    }
}

// ---------------------------------------------------------------------------
// K5: fused edge-message + per-node aggregation. Wave per node (grid-stride).
// Per 64-edge batch the (e,s) pairs sit in each lane's int2; per edge they
// are broadcast with v_readlane (1 instr, SGPR result). Rotating software
// pipeline: while FMA-ing edge j, edge j+1's Ps row gather and 32-float
// edge row (uniform address -> SMEM loads) are already in flight, hidden
// under the 64-cycle FMA chain. No LDS -> no occupancy cost.
// ---------------------------------------------------------------------------
__global__ void __launch_bounds__(256) agg_kernel(
    const float* __restrict__ edge,
    const float* __restrict__ W_e, const float* __restrict__ b_e,
    const float* __restrict__ Ps, const float* __restrict__ Pd,
    const int* __restrict__ row_start, const int2* __restrict__ csr,
    float* __restrict__ msum, int n_nodes)
{
    const int lane = threadIdx.x & 63;
    const int wid  = __builtin_amdgcn_readfirstlane((int)(threadIdx.x >> 6));
    const int wpb  = blockDim.x >> 6;
    const int gw   = blockIdx.x * wpb + wid;
    const int nw   = gridDim.x * wpb;

    float Wm[32];
#pragma unroll
    for (int k = 0; k < 32; ++k)
        Wm[k] = W_e[(64 + k) * DO + lane];
    const float bj = b_e[lane];

    for (int n = gw; n < n_nodes; n += nw) {
        const float base_m = bj + Pd[(unsigned)n * DO + lane];
        const int beg = row_start[n], end = row_start[n + 1];
        float acc = 0.f;

        for (int b0 = beg; b0 < end; b0 += 64) {
            const int cnt = min(end - b0, 64);
            const int2 my = csr[min(b0 + lane, end - 1)];

            // pipeline prologue: issue edge 0's loads
            int e0 = __builtin_amdgcn_readlane(my.x, 0);
            int s0 = __builtin_amdgcn_readlane(my.y, 0);
            float ps_n = Ps[(unsigned)s0 * DO + lane];
            const float* __restrict__ er_n = edge + (size_t)e0 * DE;
            float4 rn0 = *(const float4*)(er_n +  0);
            float4 rn1 = *(const float4*)(er_n +  4);
            float4 rn2 = *(const float4*)(er_n +  8);
            float4 rn3 = *(const float4*)(er_n + 12);
            float4 rn4 = *(const float4*)(er_n + 16);
            float4 rn5 = *(const float4*)(er_n + 20);
            float4 rn6 = *(const float4*)(er_n + 24);
            float4 rn7 = *(const float4*)(er_n + 28);

            for (int j = 0; j < cnt; ++j) {
                const float ps_c = ps_n;
                const float4 c0 = rn0, c1 = rn1, c2 = rn2, c3 = rn3;
                const float4 c4 = rn4, c5 = rn5, c6 = rn6, c7 = rn7;
                if (j + 1 < cnt) {   // issue next edge's loads (uniform branch)
                    int e1 = __builtin_amdgcn_readlane(my.x, j + 1);
                    int s1 = __builtin_amdgcn_readlane(my.y, j + 1);
                    ps_n = Ps[(unsigned)s1 * DO + lane];
                    const float* __restrict__ p = edge + (size_t)e1 * DE;
                    rn0 = *(const float4*)(p +  0);
                    rn1 = *(const float4*)(p +  4);
                    rn2 = *(const float4*)(p +  8);
                    rn3 = *(const float4*)(p + 12);
                    rn4 = *(const float4*)(p + 16);
                    rn5 = *(const float4*)(p + 20);
                    rn6 = *(const float4*)(p + 24);
                    rn7 = *(const float4*)(p + 28);
                }
                float m0 = base_m + ps_c, m1 = 0.f, m2 = 0.f, m3 = 0.f;
                m0 = fmaf(c0.x, Wm[ 0], m0); m1 = fmaf(c0.y, Wm[ 1], m1);
                m2 = fmaf(c0.z, Wm[ 2], m2); m3 = fmaf(c0.w, Wm[ 3], m3);
                m0 = fmaf(c1.x, Wm[ 4], m0); m1 = fmaf(c1.y, Wm[ 5], m1);
                m2 = fmaf(c1.z, Wm[ 6], m2); m3 = fmaf(c1.w, Wm[ 7], m3);
                m0 = fmaf(c2.x, Wm[ 8], m0); m1 = fmaf(c2.y, Wm[ 9], m1);
                m2 = fmaf(c2.z, Wm[10], m2); m3 = fmaf(c2.w, Wm[11], m3);
                m0 = fmaf(c3.x, Wm[12], m0); m1 = fmaf(c3.y, Wm[13], m1);
                m2 = fmaf(c3.z, Wm[14], m2); m3 = fmaf(c3.w, Wm[15], m3);
                m0 = fmaf(c4.x, Wm[16], m0); m1 = fmaf(c4.y, Wm[17], m1);
                m2 = fmaf(c4.z, Wm[18], m2); m3 = fmaf(c4.w, Wm[19], m3);
                m0 = fmaf(c5.x, Wm[20], m0); m1 = fmaf(c5.y, Wm[21], m1);
                m2 = fmaf(c5.z, Wm[22], m2); m3 = fmaf(c5.w, Wm[23], m3);
                m0 = fmaf(c6.x, Wm[24], m0); m1 = fmaf(c6.y, Wm[25], m1);
                m2 = fmaf(c6.z, Wm[26], m2); m3 = fmaf(c6.w, Wm[27], m3);
                m0 = fmaf(c7.x, Wm[28], m0); m1 = fmaf(c7.y, Wm[29], m1);
                m2 = fmaf(c7.z, Wm[30], m2); m3 = fmaf(c7.w, Wm[31], m3);
                acc += fmaxf((m0 + m1) + (m2 + m3), 0.f);
            }
        }
        msum[(unsigned)n * DO + lane] = acc;
    }
}

// ---------------------------------------------------------------------------
// K6: node update: out = relu((msum/deg)@W_v[0:64] + node@W_v[64:128] + b_v)
// ---------------------------------------------------------------------------
__global__ void __launch_bounds__(256) node_out_kernel(
    const float* __restrict__ node, const float* __restrict__ msum,
    const int* __restrict__ row_start,
    const float* __restrict__ W_v, const float* __restrict__ b_v,
    float* __restrict__ out, int n_nodes)
{
    const int lane = threadIdx.x & 63;
    const int wid  = __builtin_amdgcn_readfirstlane((int)(threadIdx.x >> 6));
    const int wpb  = blockDim.x >> 6;
    const int gw   = blockIdx.x * wpb + wid;
    const int nw   = gridDim.x * wpb;

    float Wt[64], Wb[64];
#pragma unroll
    for (int k = 0; k < 64; ++k) {
        Wt[k] = W_v[k * DO + lane];
        Wb[k] = W_v[(64 + k) * DO + lane];
    }
    const float bj = b_v[lane];

    for (int n = gw; n < n_nodes; n += nw) {
        const float* __restrict__ ms = msum + (size_t)n * DO;
        const float* __restrict__ x  = node + (size_t)n * DN;
        const float dg = (float)(row_start[n + 1] - row_start[n]);
        float an = 0.f, ax = 0.f;
#pragma unroll
        for (int k = 0; k < 64; ++k) {
            an = fmaf(ms[k], Wt[k], an);
            ax = fmaf(x[k],  Wb[k], ax);
        }
        float acc = bj + ax + (dg > 0.f ? an / dg : 0.f);
        out[(size_t)n * DO + lane] = fmaxf(acc, 0.f);
    }
}

extern "C" void kernel_launch(void* const* d_in, const int* in_sizes, int n_in,
                              void* d_out, int out_size, void* d_ws, size_t ws_size,
                              hipStream_t stream)
{
    const float* node = (const float*)d_in[0];
    const float* edge = (const float*)d_in[1];
    const int*   src  = (const int*)d_in[2];
    const int*   dst  = (const int*)d_in[3];
    const float* W_e  = (const float*)d_in[4];
    const float* b_e  = (const float*)d_in[5];
    const float* W_v  = (const float*)d_in[6];
    const float* b_v  = (const float*)d_in[7];
    float* out = (float*)d_out;

    const int n_nodes = in_sizes[0] / DN;
    const int n_edges = in_sizes[2];

    // Workspace: Ps | Pd | msum (floats) | row_start | cnt | cursor | local | bsum | csr(int2)
    float* Ps   = (float*)d_ws;
    float* Pd   = Ps   + (size_t)n_nodes * DO;
    float* msum = Pd   + (size_t)n_nodes * DO;
    int* row_start = (int*)(msum + (size_t)n_nodes * DO);
    int* cnt       = row_start + (n_nodes + 1);
    int* cursor    = cnt + n_nodes;
    int* local     = cursor + n_nodes;
    int* bsum      = local + n_nodes;
    int2* csr      = (int2*)(((size_t)(bsum + NB) + 15) & ~(size_t)15);

    hipMemsetAsync(cnt, 0, (size_t)n_nodes * sizeof(int), stream);

    node_pre_kernel<<<512, 256, 0, stream>>>(node, W_e, Ps, Pd, n_nodes);
    hist_kernel<<<(n_edges + 255) / 256, 256, 0, stream>>>(dst, cnt, n_edges);
    scan_partial<<<NB, 256, 0, stream>>>(cnt, local, bsum, n_nodes);
    scan_bsum<<<1, NB, 0, stream>>>(bsum, row_start, n_nodes);
    scan_add<<<NB, 256, 0, stream>>>(local, bsum, row_start, cursor, n_nodes);
    scatter_kernel<<<(n_edges + 255) / 256, 256, 0, stream>>>(dst, src, cursor, csr, n_edges);
    agg_kernel<<<2048, 256, 0, stream>>>(edge, W_e, b_e, Ps, Pd,
                                         row_start, csr, msum, n_nodes);
    node_out_kernel<<<512, 256, 0, stream>>>(node, msum, row_start, W_v, b_v,
                                             out, n_nodes);
}